// Round 2
// baseline (116.528 us; speedup 1.0000x reference)
//
#include <hip/hip_runtime.h>

#define VOCAB 50257
#define EMBED 256
#define OUT 5
#define ROWSTRIDE 8   // embW row padded to 8 floats for aligned dwordx4 gathers
#define BATCH 512
#define SEQ 512

// Kernel 1: embW[v][0..4] = emb[v,:] @ W[o,:]  -- one wave per vocab row,
// grid-stride over rows so W is LDS-staged only once per block.
__global__ __launch_bounds__(256) void k_embw(const float* __restrict__ emb,
                                              const float* __restrict__ W,
                                              float* __restrict__ embW) {
    __shared__ float sW[OUT * EMBED];
    for (int i = threadIdx.x; i < OUT * EMBED; i += 256) sW[i] = W[i];
    __syncthreads();

    const int lane   = threadIdx.x & 63;
    const int waveId = blockIdx.x * 4 + (threadIdx.x >> 6);
    const int nWaves = gridDim.x * 4;

    // Preload this lane's W fragments once (registers, reused across rows).
    float4 w[OUT];
#pragma unroll
    for (int o = 0; o < OUT; ++o)
        w[o] = *(const float4*)(sW + o * EMBED + lane * 4);

    for (int v = waveId; v < VOCAB; v += nWaves) {
        const float4 e = *(const float4*)(emb + (size_t)v * EMBED + lane * 4);
        float p[OUT];
#pragma unroll
        for (int o = 0; o < OUT; ++o)
            p[o] = e.x * w[o].x + e.y * w[o].y + e.z * w[o].z + e.w * w[o].w;

#pragma unroll
        for (int o = 0; o < OUT; ++o) {
#pragma unroll
            for (int off = 32; off > 0; off >>= 1)
                p[o] += __shfl_down(p[o], off, 64);
        }
        if (lane == 0) {
            float* r = embW + (size_t)v * ROWSTRIDE;
#pragma unroll
            for (int o = 0; o < OUT; ++o) r[o] = p[o];
        }
    }
}

// Kernel 2 (fused pool + logits + log-softmax + NLL + mean):
// one block per sample; block's scalar loss atomically added to out[0].
__global__ __launch_bounds__(256) void k_pool(const int* __restrict__ x,
                                              const int* __restrict__ lengths,
                                              const int* __restrict__ y,
                                              const float* __restrict__ bias,
                                              const float* __restrict__ embW,
                                              float* __restrict__ out) {
    const int b = blockIdx.x;
    const int len = lengths[b];
    const int* xb = x + (size_t)b * SEQ;

    float acc[OUT] = {0.f, 0.f, 0.f, 0.f, 0.f};
    for (int s = threadIdx.x; s < len; s += 256) {
        const float* r = embW + (size_t)xb[s] * ROWSTRIDE;
        const float4 r0 = *(const float4*)(r);
        const float  r4 = r[4];
        acc[0] += r0.x; acc[1] += r0.y; acc[2] += r0.z; acc[3] += r0.w;
        acc[4] += r4;
    }

#pragma unroll
    for (int o = 0; o < OUT; ++o) {
#pragma unroll
        for (int off = 32; off > 0; off >>= 1)
            acc[o] += __shfl_down(acc[o], off, 64);
    }

    __shared__ float red[4][OUT];
    const int wave = threadIdx.x >> 6;
    const int lane = threadIdx.x & 63;
    if (lane == 0) {
#pragma unroll
        for (int o = 0; o < OUT; ++o) red[wave][o] = acc[o];
    }
    __syncthreads();

    if (threadIdx.x == 0) {
        float logits[OUT];
        const float inv = 1.0f / (float)len;
#pragma unroll
        for (int o = 0; o < OUT; ++o)
            logits[o] = (red[0][o] + red[1][o] + red[2][o] + red[3][o]) * inv + bias[o];

        float m = logits[0];
#pragma unroll
        for (int o = 1; o < OUT; ++o) m = fmaxf(m, logits[o]);
        float sum = 0.f;
#pragma unroll
        for (int o = 0; o < OUT; ++o) sum += __expf(logits[o] - m);
        const float lse = m + __logf(sum);
        const float loss = lse - logits[y[b]];
        atomicAdd(out, loss * (1.0f / (float)BATCH));
    }
}

extern "C" void kernel_launch(void* const* d_in, const int* in_sizes, int n_in,
                              void* d_out, int out_size, void* d_ws, size_t ws_size,
                              hipStream_t stream) {
    const int*   x       = (const int*)d_in[0];
    const int*   lengths = (const int*)d_in[1];
    const int*   y       = (const int*)d_in[2];
    const float* emb     = (const float*)d_in[3];
    const float* W       = (const float*)d_in[4];
    const float* bias    = (const float*)d_in[5];

    float* embW = (float*)d_ws;  // VOCAB * ROWSTRIDE floats (~1.6 MB)

    // d_out is poisoned 0xAA before every timed launch; zero it for atomicAdd.
    hipMemsetAsync(d_out, 0, sizeof(float), stream);

    k_embw<<<2048, 256, 0, stream>>>(emb, W, embW);
    k_pool<<<BATCH, 256, 0, stream>>>(x, lengths, y, bias, embW, (float*)d_out);
}